// Round 9
// baseline (77.757 us; speedup 1.0000x reference)
//
#include <hip/hip_runtime.h>
#include <math.h>

#define NTOK 784
#define DIM 128
#define FFD 512

// ========== K1: zero(out) + posw (325 blocks, 32x64) || LN1+qkv (150 blocks) ==========
__global__ __launch_bounds__(256) void posw_qkv3(
    const float* __restrict__ pu, const float* __restrict__ pv, float* __restrict__ W,
    const float* __restrict__ x, const float* __restrict__ g, const float* __restrict__ b,
    const float* __restrict__ wq, const float* __restrict__ wk, const float* __restrict__ wv,
    float* __restrict__ q, float* __restrict__ ek, float* __restrict__ vv,
    float* __restrict__ out) {
  __shared__ float smem[12288];  // 48 KB union
  int tid = threadIdx.x;

  // zero the output accumulator (atomics target for K3)
  for (int i = blockIdx.x * 256 + tid; i < NTOK * DIM; i += 475 * 256) out[i] = 0.f;

  if (blockIdx.x < 325) {
    // posw: 32x64 tile, full K staged once
    float (*As)[32] = (float(*)[32])smem;           // [128][32]
    float (*Bs)[64] = (float(*)[64])(smem + 4096);  // [128][64]
    int m0 = (blockIdx.x % 25) * 32, n0 = (blockIdx.x / 25) * 64;
    {
      int r = tid >> 3, kq = (tid & 7) * 16;
      int gm = min(m0 + r, NTOK - 1);
#pragma unroll
      for (int j = 0; j < 4; ++j) {
        float4 a = *(const float4*)&pu[gm * DIM + kq + j * 4];
        As[kq + j * 4 + 0][r] = a.x; As[kq + j * 4 + 1][r] = a.y;
        As[kq + j * 4 + 2][r] = a.z; As[kq + j * 4 + 3][r] = a.w;
      }
      int rb = tid >> 2, kb = (tid & 3) * 32;
      int gn = min(n0 + rb, NTOK - 1);
#pragma unroll
      for (int j = 0; j < 8; ++j) {
        float4 v = *(const float4*)&pv[gn * DIM + kb + j * 4];
        Bs[kb + j * 4 + 0][rb] = v.x; Bs[kb + j * 4 + 1][rb] = v.y;
        Bs[kb + j * 4 + 2][rb] = v.z; Bs[kb + j * 4 + 3][rb] = v.w;
      }
    }
    __syncthreads();
    int tx = tid & 15, ty = tid >> 4;  // 2 rows x 4 cols per thread
    float acc[2][4] = {};
#pragma unroll 8
    for (int kk = 0; kk < DIM; ++kk) {
      float2 a2 = *(const float2*)&As[kk][ty * 2];
      float4 b4 = *(const float4*)&Bs[kk][tx * 4];
      float av[2] = {a2.x, a2.y};
      float bv[4] = {b4.x, b4.y, b4.z, b4.w};
#pragma unroll
      for (int i = 0; i < 2; ++i)
#pragma unroll
        for (int j = 0; j < 4; ++j) acc[i][j] = fmaf(av[i], bv[j], acc[i][j]);
    }
    int c0 = n0 + tx * 4;
    if (c0 + 3 < NTOK) {
#pragma unroll
      for (int i = 0; i < 2; ++i) {
        int gr = m0 + ty * 2 + i;
        if (gr < NTOK) {
          float4 o = {expf(acc[i][0]), expf(acc[i][1]), expf(acc[i][2]), expf(acc[i][3])};
          *(float4*)&W[gr * NTOK + c0] = o;
        }
      }
    }
  } else {
    // qkv: LN1 + one of {q,k,v} half, 32-row tile
    float (*Xs)[32] = (float(*)[32])smem;            // [128][32]
    float (*Bq)[64] = (float(*)[64])(smem + 4096);   // [64][64]
    float* redS = smem + 8192;                       // [8][32]
    float* redQ = smem + 8448;
    int bid = blockIdx.x - 325;
    int m0 = (bid % 25) * 32;
    int ct = bid / 25;
    int wsel = ct >> 1;
    int n0 = (ct & 1) * 64;
    const float* B = (wsel == 0) ? wq : (wsel == 1) ? wk : wv;

    if (m0 + 32 <= NTOK) {
#pragma unroll
      for (int it = 0; it < 4; ++it) {
        int idx = it * 256 + tid;
        int c = idx >> 3, j4 = (idx & 7) * 4;
        float4 v = *(const float4*)&x[c * NTOK + m0 + j4];
        Xs[c][j4 + 0] = v.x; Xs[c][j4 + 1] = v.y; Xs[c][j4 + 2] = v.z; Xs[c][j4 + 3] = v.w;
      }
    } else {
#pragma unroll
      for (int it = 0; it < 4; ++it) {
        int idx = it * 256 + tid;
        int c = idx >> 3, j4 = (idx & 7) * 4;
#pragma unroll
        for (int u = 0; u < 4; ++u) {
          int n = min(m0 + j4 + u, NTOK - 1);
          Xs[c][j4 + u] = x[c * NTOK + n];
        }
      }
    }
    __syncthreads();

    int n = tid & 31, grp = tid >> 5;   // 8 groups x 16 channels
    float s = 0.f, ss = 0.f;
    for (int c = grp * 16; c < grp * 16 + 16; ++c) { float v = Xs[c][n]; s += v; ss += v * v; }
    redS[grp * 32 + n] = s; redQ[grp * 32 + n] = ss;
    __syncthreads();
    float sum = 0.f, sq = 0.f;
#pragma unroll
    for (int gi = 0; gi < 8; ++gi) { sum += redS[gi * 32 + n]; sq += redQ[gi * 32 + n]; }
    float mu = sum * (1.0f / DIM);
    float var = sq * (1.0f / DIM) - mu * mu;
    float rs = rsqrtf(var + 1e-5f);
    for (int c = grp * 16; c < grp * 16 + 16; ++c)
      Xs[c][n] = (Xs[c][n] - mu) * rs * g[c] + b[c];

    int tx = tid & 15, ty = tid >> 4;
    float acc[2][4] = {};
#pragma unroll
    for (int h = 0; h < 2; ++h) {
      {
        int r = tid >> 2, kq = (tid & 3) * 16;
#pragma unroll
        for (int j = 0; j < 4; ++j) {
          float4 v = *(const float4*)&B[(n0 + r) * DIM + h * 64 + kq + j * 4];
          Bq[kq + j * 4 + 0][r] = v.x; Bq[kq + j * 4 + 1][r] = v.y;
          Bq[kq + j * 4 + 2][r] = v.z; Bq[kq + j * 4 + 3][r] = v.w;
        }
      }
      __syncthreads();
#pragma unroll 4
      for (int kk = 0; kk < 64; ++kk) {
        float2 a2 = *(const float2*)&Xs[h * 64 + kk][ty * 2];
        float4 b4 = *(const float4*)&Bq[kk][tx * 4];
        float av[2] = {a2.x, a2.y};
        float bv[4] = {b4.x, b4.y, b4.z, b4.w};
#pragma unroll
        for (int i = 0; i < 2; ++i)
#pragma unroll
          for (int j = 0; j < 4; ++j) acc[i][j] = fmaf(av[i], bv[j], acc[i][j]);
      }
      __syncthreads();
    }
    int c0 = n0 + tx * 4;
    float* dst = (wsel == 0) ? q : (wsel == 1) ? ek : vv;
#pragma unroll
    for (int i = 0; i < 2; ++i) {
      int gr = m0 + ty * 2 + i;
      if (gr < NTOK) {
        float4 o;
        if (wsel == 0) {
          o.x = 1.0f / (1.0f + expf(-acc[i][0]));
          o.y = 1.0f / (1.0f + expf(-acc[i][1]));
          o.z = 1.0f / (1.0f + expf(-acc[i][2]));
          o.w = 1.0f / (1.0f + expf(-acc[i][3]));
        } else if (wsel == 1) {
          o.x = expf(acc[i][0]); o.y = expf(acc[i][1]);
          o.z = expf(acc[i][2]); o.w = expf(acc[i][3]);
        } else {
          o.x = acc[i][0]; o.y = acc[i][1]; o.z = acc[i][2]; o.w = acc[i][3];
        }
        *(float4*)&dst[gr * DIM + c0] = o;
      }
    }
  }
}

// ========== K2: agg, split-8, 32-row tiles, grid (25,2,8), 256 thr ==========
__global__ __launch_bounds__(256) void agg32(
    const float* __restrict__ W, const float* __restrict__ ek,
    const float* __restrict__ vv, float* __restrict__ nump, float* __restrict__ denp) {
  __shared__ float As[96][32];
  __shared__ float Bn[96][64];
  __shared__ float Bd[96][64];
  int tid = threadIdx.x;
  int m0 = blockIdx.x * 32, d0 = blockIdx.y * 64, sp = blockIdx.z;
  int tx = tid & 15, ty = tid >> 4;         // 2 rows x 4 cols
  int ra = tid >> 3, ka = (tid & 7) * 4;
  int kb = tid >> 3, db = (tid & 7) * 8;
  int gm = min(m0 + ra, NTOK - 1);
  float an[2][4] = {}, ad[2][4] = {};
  int tlo = (sp * 25) / 8, thi = ((sp + 1) * 25) / 8;
  for (int base = tlo; base < thi; base += 3) {
    int nt = min(3, thi - base);
    for (int t = 0; t < nt; ++t) {
      int k0 = (base + t) * 32;
      int lk = t * 32;
      if (k0 + 32 <= NTOK) {
        float4 a = *(const float4*)&W[gm * NTOK + k0 + ka];
        As[lk + ka + 0][ra] = a.x; As[lk + ka + 1][ra] = a.y;
        As[lk + ka + 2][ra] = a.z; As[lk + ka + 3][ra] = a.w;
        int gk = k0 + kb;
        float4 e0 = *(const float4*)&ek[gk * DIM + d0 + db];
        float4 e1 = *(const float4*)&ek[gk * DIM + d0 + db + 4];
        float4 w0 = *(const float4*)&vv[gk * DIM + d0 + db];
        float4 w1_ = *(const float4*)&vv[gk * DIM + d0 + db + 4];
        Bd[lk + kb][db + 0] = e0.x; Bd[lk + kb][db + 1] = e0.y;
        Bd[lk + kb][db + 2] = e0.z; Bd[lk + kb][db + 3] = e0.w;
        Bd[lk + kb][db + 4] = e1.x; Bd[lk + kb][db + 5] = e1.y;
        Bd[lk + kb][db + 6] = e1.z; Bd[lk + kb][db + 7] = e1.w;
        Bn[lk + kb][db + 0] = e0.x * w0.x; Bn[lk + kb][db + 1] = e0.y * w0.y;
        Bn[lk + kb][db + 2] = e0.z * w0.z; Bn[lk + kb][db + 3] = e0.w * w0.w;
        Bn[lk + kb][db + 4] = e1.x * w1_.x; Bn[lk + kb][db + 5] = e1.y * w1_.y;
        Bn[lk + kb][db + 6] = e1.z * w1_.z; Bn[lk + kb][db + 7] = e1.w * w1_.w;
      } else {
#pragma unroll
        for (int j = 0; j < 4; ++j) {
          int gk = k0 + ka + j;
          As[lk + ka + j][ra] = (gk < NTOK) ? W[gm * NTOK + gk] : 0.f;
        }
        int gk = k0 + kb;
        if (gk < NTOK) {
          float4 e0 = *(const float4*)&ek[gk * DIM + d0 + db];
          float4 e1 = *(const float4*)&ek[gk * DIM + d0 + db + 4];
          float4 w0 = *(const float4*)&vv[gk * DIM + d0 + db];
          float4 w1_ = *(const float4*)&vv[gk * DIM + d0 + db + 4];
          Bd[lk + kb][db + 0] = e0.x; Bd[lk + kb][db + 1] = e0.y;
          Bd[lk + kb][db + 2] = e0.z; Bd[lk + kb][db + 3] = e0.w;
          Bd[lk + kb][db + 4] = e1.x; Bd[lk + kb][db + 5] = e1.y;
          Bd[lk + kb][db + 6] = e1.z; Bd[lk + kb][db + 7] = e1.w;
          Bn[lk + kb][db + 0] = e0.x * w0.x; Bn[lk + kb][db + 1] = e0.y * w0.y;
          Bn[lk + kb][db + 2] = e0.z * w0.z; Bn[lk + kb][db + 3] = e0.w * w0.w;
          Bn[lk + kb][db + 4] = e1.x * w1_.x; Bn[lk + kb][db + 5] = e1.y * w1_.y;
          Bn[lk + kb][db + 6] = e1.z * w1_.z; Bn[lk + kb][db + 7] = e1.w * w1_.w;
        } else {
#pragma unroll
          for (int j = 0; j < 8; ++j) { Bd[lk + kb][db + j] = 0.f; Bn[lk + kb][db + j] = 0.f; }
        }
      }
    }
    __syncthreads();
    int nk = nt * 32;
    for (int kk = 0; kk < nk; ++kk) {
      float2 a2 = *(const float2*)&As[kk][ty * 2];
      float4 n4 = *(const float4*)&Bn[kk][tx * 4];
      float4 d4 = *(const float4*)&Bd[kk][tx * 4];
      float av[2] = {a2.x, a2.y};
      float nv[4] = {n4.x, n4.y, n4.z, n4.w};
      float dv[4] = {d4.x, d4.y, d4.z, d4.w};
#pragma unroll
      for (int i = 0; i < 2; ++i)
#pragma unroll
        for (int j = 0; j < 4; ++j) {
          an[i][j] = fmaf(av[i], nv[j], an[i][j]);
          ad[i][j] = fmaf(av[i], dv[j], ad[i][j]);
        }
    }
    __syncthreads();
  }
#pragma unroll
  for (int i = 0; i < 2; ++i) {
    int gr = m0 + ty * 2 + i;
    if (gr < NTOK) {
      float4 on = {an[i][0], an[i][1], an[i][2], an[i][3]};
      float4 od = {ad[i][0], ad[i][1], ad[i][2], ad[i][3]};
      *(float4*)&nump[(sp * NTOK + gr) * DIM + d0 + tx * 4] = on;
      *(float4*)&denp[(sp * NTOK + gr) * DIM + d0 + tx * 4] = od;
    }
  }
}

// ========== K3: gate + proj + residual + LN2 + ff1(gelu) + ff2, grid (98,8), 256 thr ==========
// Each block: 8 rows (m), one 64-wide f-slice. proj/LN2 recomputed per f-slice (x8, cheap).
// All contributions atomicAdd into out (zeroed by K1); y==0 also adds t2 + b2f.
__global__ __launch_bounds__(256) void epi_fused(
    const float* __restrict__ q, const float* __restrict__ nump,
    const float* __restrict__ denp, const float* __restrict__ wo,
    const float* __restrict__ bo, const float* __restrict__ x,
    const float* __restrict__ g2, const float* __restrict__ b2n,
    const float* __restrict__ w1, const float* __restrict__ b1f,
    const float* __restrict__ w2, const float* __restrict__ b2f,
    float* __restrict__ out) {
  __shared__ float At[DIM][9];        // gated attn, k-major (4.6 KB)
  __shared__ float Ws[DIM * DIM];     // 64 KB: wo k-major; later w1 [128][64] + w2 [64][128]
  __shared__ float Fn[DIM][9];        // LN2 out, k-major
  __shared__ float P[64][9];          // gelu(ff1) slice, k-major
  int tid = threadIdx.x;
  int m0 = blockIdx.x * 8;            // 98*8 = 784
  int f0 = blockIdx.y * 64;

  // --- Phase A: gate -> At; stage wo k-major
  {
    int nn = tid >> 5, c4 = (tid & 31) * 4;
    int base = (m0 + nn) * DIM + c4;
    float4 qv = *(const float4*)&q[base];
    float4 nv = {0.f, 0.f, 0.f, 0.f}, dv = {0.f, 0.f, 0.f, 0.f};
#pragma unroll
    for (int s = 0; s < 8; ++s) {
      float4 a = *(const float4*)&nump[s * NTOK * DIM + base];
      float4 d = *(const float4*)&denp[s * NTOK * DIM + base];
      nv.x += a.x; nv.y += a.y; nv.z += a.z; nv.w += a.w;
      dv.x += d.x; dv.y += d.y; dv.z += d.z; dv.w += d.w;
    }
    At[c4 + 0][nn] = qv.x * (nv.x / dv.x);
    At[c4 + 1][nn] = qv.y * (nv.y / dv.y);
    At[c4 + 2][nn] = qv.z * (nv.z / dv.z);
    At[c4 + 3][nn] = qv.w * (nv.w / dv.w);
  }
  {
    int r = tid >> 1, kq = (tid & 1) * 64;
#pragma unroll
    for (int j = 0; j < 16; ++j) {
      float4 v = *(const float4*)&wo[r * DIM + kq + j * 4];
      Ws[(kq + j * 4 + 0) * DIM + r] = v.x; Ws[(kq + j * 4 + 1) * DIM + r] = v.y;
      Ws[(kq + j * 4 + 2) * DIM + r] = v.z; Ws[(kq + j * 4 + 3) * DIM + r] = v.w;
    }
  }
  __syncthreads();

  // --- Phase B: O-proj + residual + LN2 (8 rows x 32 lanes x 4 c)
  int row = tid >> 5, c4 = (tid & 31) * 4;
  int gn = m0 + row;
  float tv[4];
  {
    float acc[4] = {0.f, 0.f, 0.f, 0.f};
#pragma unroll 4
    for (int kk = 0; kk < DIM; ++kk) {
      float a = At[kk][row];
      float4 b4 = *(const float4*)&Ws[kk * DIM + c4];
      acc[0] = fmaf(a, b4.x, acc[0]);
      acc[1] = fmaf(a, b4.y, acc[1]);
      acc[2] = fmaf(a, b4.z, acc[2]);
      acc[3] = fmaf(a, b4.w, acc[3]);
    }
    float4 bias = *(const float4*)&bo[c4];
    float o0 = acc[0] + bias.x + x[(c4 + 0) * NTOK + gn];
    float o1 = acc[1] + bias.y + x[(c4 + 1) * NTOK + gn];
    float o2 = acc[2] + bias.z + x[(c4 + 2) * NTOK + gn];
    float o3 = acc[3] + bias.w + x[(c4 + 3) * NTOK + gn];
    float4 bf = *(const float4*)&b2f[c4];
    tv[0] = o0 + bf.x; tv[1] = o1 + bf.y; tv[2] = o2 + bf.z; tv[3] = o3 + bf.w;

    float s = o0 + o1 + o2 + o3;
    float ss = o0 * o0 + o1 * o1 + o2 * o2 + o3 * o3;
#pragma unroll
    for (int off = 1; off < 32; off <<= 1) {
      s += __shfl_xor(s, off);
      ss += __shfl_xor(ss, off);
    }
    float mu = s * (1.0f / DIM);
    float var = ss * (1.0f / DIM) - mu * mu;
    float rs = rsqrtf(var + 1e-5f);
    float4 gg = *(const float4*)&g2[c4];
    float4 bb = *(const float4*)&b2n[c4];
    Fn[c4 + 0][row] = (o0 - mu) * rs * gg.x + bb.x;
    Fn[c4 + 1][row] = (o1 - mu) * rs * gg.y + bb.y;
    Fn[c4 + 2][row] = (o2 - mu) * rs * gg.z + bb.z;
    Fn[c4 + 3][row] = (o3 - mu) * rs * gg.w + bb.w;
  }
  __syncthreads();   // Ws reads done, Fn complete

  // --- Phase C: stage w1 slice [128][64] at Ws, w2 slice [64][128] at Ws+8192
  {
    int rw = tid >> 2, kw = (tid & 3) * 32;
#pragma unroll
    for (int j = 0; j < 8; ++j) {
      float4 v = *(const float4*)&w1[(f0 + rw) * DIM + kw + j * 4];
      Ws[(kw + j * 4 + 0) * 64 + rw] = v.x; Ws[(kw + j * 4 + 1) * 64 + rw] = v.y;
      Ws[(kw + j * 4 + 2) * 64 + rw] = v.z; Ws[(kw + j * 4 + 3) * 64 + rw] = v.w;
    }
    float* W2s = Ws + 8192;
    int c = tid >> 1, fq = (tid & 1) * 32;
#pragma unroll
    for (int j = 0; j < 8; ++j) {
      float4 v = *(const float4*)&w2[c * FFD + f0 + fq + j * 4];
      W2s[(fq + j * 4 + 0) * DIM + c] = v.x; W2s[(fq + j * 4 + 1) * DIM + c] = v.y;
      W2s[(fq + j * 4 + 2) * DIM + c] = v.z; W2s[(fq + j * 4 + 3) * DIM + c] = v.w;
    }
  }
  __syncthreads();

  // --- Phase D: ff1 + gelu (8 rows x 32 lanes x 2 f)
  {
    int f2 = (tid & 31) * 2;
    float a0 = 0.f, a1 = 0.f;
#pragma unroll 4
    for (int kk = 0; kk < DIM; ++kk) {
      float a = Fn[kk][row];
      float2 w = *(const float2*)&Ws[kk * 64 + f2];
      a0 = fmaf(a, w.x, a0);
      a1 = fmaf(a, w.y, a1);
    }
    float2 b1v = *(const float2*)&b1f[f0 + f2];
    float v0 = a0 + b1v.x, v1 = a1 + b1v.y;
    P[f2 + 0][row] = 0.5f * v0 * (1.0f + erff(v0 * 0.70710678118654752f));
    P[f2 + 1][row] = 0.5f * v1 * (1.0f + erff(v1 * 0.70710678118654752f));
  }
  __syncthreads();

  // --- Phase E: ff2 partial (8 rows x 32 lanes x 4 c) + atomic accumulate
  {
    const float* W2s = Ws + 8192;
    float acc[4] = {0.f, 0.f, 0.f, 0.f};
#pragma unroll 4
    for (int f = 0; f < 64; ++f) {
      float p = P[f][row];
      float4 w4 = *(const float4*)&W2s[f * DIM + c4];
      acc[0] = fmaf(p, w4.x, acc[0]);
      acc[1] = fmaf(p, w4.y, acc[1]);
      acc[2] = fmaf(p, w4.z, acc[2]);
      acc[3] = fmaf(p, w4.w, acc[3]);
    }
    if (blockIdx.y == 0) {
      acc[0] += tv[0]; acc[1] += tv[1]; acc[2] += tv[2]; acc[3] += tv[3];
    }
    atomicAdd(&out[(c4 + 0) * NTOK + gn], acc[0]);
    atomicAdd(&out[(c4 + 1) * NTOK + gn], acc[1]);
    atomicAdd(&out[(c4 + 2) * NTOK + gn], acc[2]);
    atomicAdd(&out[(c4 + 3) * NTOK + gn], acc[3]);
  }
}

extern "C" void kernel_launch(void* const* d_in, const int* in_sizes, int n_in,
                              void* d_out, int out_size, void* d_ws, size_t ws_size,
                              hipStream_t stream) {
  const float* x   = (const float*)d_in[0];
  const float* wq  = (const float*)d_in[1];
  const float* wk  = (const float*)d_in[2];
  const float* wv  = (const float*)d_in[3];
  const float* wo  = (const float*)d_in[4];
  const float* bo  = (const float*)d_in[5];
  const float* pu  = (const float*)d_in[6];
  const float* pv  = (const float*)d_in[7];
  const float* g1  = (const float*)d_in[8];
  const float* b1n = (const float*)d_in[9];
  const float* g2  = (const float*)d_in[10];
  const float* b2n = (const float*)d_in[11];
  const float* w1  = (const float*)d_in[12];
  const float* b1f = (const float*)d_in[13];
  const float* w2  = (const float*)d_in[14];
  const float* b2f = (const float*)d_in[15];
  float* out = (float*)d_out;

  float* ws = (float*)d_ws;
  float* q    = ws;                 // [784,128]
  float* ek   = ws + 100352;        // [784,128]
  float* vv   = ws + 200704;        // [784,128]
  float* W    = ws + 301056;        // [784,784]
  float* nump = ws + 915712;        // [8,784,128]
  float* denp = ws + 1718528;       // [8,784,128]

  posw_qkv3<<<475, 256, 0, stream>>>(pu, pv, W, x, g1, b1n, wq, wk, wv, q, ek, vv, out);
  agg32<<<dim3(25, 2, 8), 256, 0, stream>>>(W, ek, vv, nump, denp);
  epi_fused<<<dim3(98, 8), 256, 0, stream>>>(q, nump, denp, wo, bo, x, g2, b2n,
                                             w1, b1f, w2, b2f, out);
}

// Round 10
// 67.856 us; speedup vs baseline: 1.1459x; 1.1459x over previous
//
#include <hip/hip_runtime.h>
#include <math.h>

#define NTOK 784
#define DIM 128
#define FFD 512

// ========== K1: posw (325 blocks, 32x64) || LN1+qkv (150 blocks, 32 rows) ==========
__global__ __launch_bounds__(256) void posw_qkv3(
    const float* __restrict__ pu, const float* __restrict__ pv, float* __restrict__ W,
    const float* __restrict__ x, const float* __restrict__ g, const float* __restrict__ b,
    const float* __restrict__ wq, const float* __restrict__ wk, const float* __restrict__ wv,
    float* __restrict__ q, float* __restrict__ ek, float* __restrict__ vv) {
  __shared__ float smem[12288];  // 48 KB union
  int tid = threadIdx.x;

  if (blockIdx.x < 325) {
    float (*As)[32] = (float(*)[32])smem;           // [128][32]
    float (*Bs)[64] = (float(*)[64])(smem + 4096);  // [128][64]
    int m0 = (blockIdx.x % 25) * 32, n0 = (blockIdx.x / 25) * 64;
    {
      int r = tid >> 3, kq = (tid & 7) * 16;
      int gm = min(m0 + r, NTOK - 1);
#pragma unroll
      for (int j = 0; j < 4; ++j) {
        float4 a = *(const float4*)&pu[gm * DIM + kq + j * 4];
        As[kq + j * 4 + 0][r] = a.x; As[kq + j * 4 + 1][r] = a.y;
        As[kq + j * 4 + 2][r] = a.z; As[kq + j * 4 + 3][r] = a.w;
      }
      int rb = tid >> 2, kb = (tid & 3) * 32;
      int gn = min(n0 + rb, NTOK - 1);
#pragma unroll
      for (int j = 0; j < 8; ++j) {
        float4 v = *(const float4*)&pv[gn * DIM + kb + j * 4];
        Bs[kb + j * 4 + 0][rb] = v.x; Bs[kb + j * 4 + 1][rb] = v.y;
        Bs[kb + j * 4 + 2][rb] = v.z; Bs[kb + j * 4 + 3][rb] = v.w;
      }
    }
    __syncthreads();
    int tx = tid & 15, ty = tid >> 4;  // 2 rows x 4 cols per thread
    float acc[2][4] = {};
#pragma unroll 8
    for (int kk = 0; kk < DIM; ++kk) {
      float2 a2 = *(const float2*)&As[kk][ty * 2];
      float4 b4 = *(const float4*)&Bs[kk][tx * 4];
      float av[2] = {a2.x, a2.y};
      float bv[4] = {b4.x, b4.y, b4.z, b4.w};
#pragma unroll
      for (int i = 0; i < 2; ++i)
#pragma unroll
        for (int j = 0; j < 4; ++j) acc[i][j] = fmaf(av[i], bv[j], acc[i][j]);
    }
    int c0 = n0 + tx * 4;
    if (c0 + 3 < NTOK) {
#pragma unroll
      for (int i = 0; i < 2; ++i) {
        int gr = m0 + ty * 2 + i;
        if (gr < NTOK) {
          float4 o = {expf(acc[i][0]), expf(acc[i][1]), expf(acc[i][2]), expf(acc[i][3])};
          *(float4*)&W[gr * NTOK + c0] = o;
        }
      }
    }
  } else {
    float (*Xs)[32] = (float(*)[32])smem;            // [128][32]
    float (*Bq)[64] = (float(*)[64])(smem + 4096);   // [64][64]
    float* redS = smem + 8192;
    float* redQ = smem + 8448;
    int bid = blockIdx.x - 325;
    int m0 = (bid % 25) * 32;
    int ct = bid / 25;
    int wsel = ct >> 1;
    int n0 = (ct & 1) * 64;
    const float* B = (wsel == 0) ? wq : (wsel == 1) ? wk : wv;

    if (m0 + 32 <= NTOK) {
#pragma unroll
      for (int it = 0; it < 4; ++it) {
        int idx = it * 256 + tid;
        int c = idx >> 3, j4 = (idx & 7) * 4;
        float4 v = *(const float4*)&x[c * NTOK + m0 + j4];
        Xs[c][j4 + 0] = v.x; Xs[c][j4 + 1] = v.y; Xs[c][j4 + 2] = v.z; Xs[c][j4 + 3] = v.w;
      }
    } else {
#pragma unroll
      for (int it = 0; it < 4; ++it) {
        int idx = it * 256 + tid;
        int c = idx >> 3, j4 = (idx & 7) * 4;
#pragma unroll
        for (int u = 0; u < 4; ++u) {
          int n = min(m0 + j4 + u, NTOK - 1);
          Xs[c][j4 + u] = x[c * NTOK + n];
        }
      }
    }
    __syncthreads();

    int n = tid & 31, grp = tid >> 5;
    float s = 0.f, ss = 0.f;
    for (int c = grp * 16; c < grp * 16 + 16; ++c) { float v = Xs[c][n]; s += v; ss += v * v; }
    redS[grp * 32 + n] = s; redQ[grp * 32 + n] = ss;
    __syncthreads();
    float sum = 0.f, sq = 0.f;
#pragma unroll
    for (int gi = 0; gi < 8; ++gi) { sum += redS[gi * 32 + n]; sq += redQ[gi * 32 + n]; }
    float mu = sum * (1.0f / DIM);
    float var = sq * (1.0f / DIM) - mu * mu;
    float rs = rsqrtf(var + 1e-5f);
    for (int c = grp * 16; c < grp * 16 + 16; ++c)
      Xs[c][n] = (Xs[c][n] - mu) * rs * g[c] + b[c];

    int tx = tid & 15, ty = tid >> 4;
    float acc[2][4] = {};
#pragma unroll
    for (int h = 0; h < 2; ++h) {
      {
        int r = tid >> 2, kq = (tid & 3) * 16;
#pragma unroll
        for (int j = 0; j < 4; ++j) {
          float4 v = *(const float4*)&B[(n0 + r) * DIM + h * 64 + kq + j * 4];
          Bq[kq + j * 4 + 0][r] = v.x; Bq[kq + j * 4 + 1][r] = v.y;
          Bq[kq + j * 4 + 2][r] = v.z; Bq[kq + j * 4 + 3][r] = v.w;
        }
      }
      __syncthreads();
#pragma unroll 4
      for (int kk = 0; kk < 64; ++kk) {
        float2 a2 = *(const float2*)&Xs[h * 64 + kk][ty * 2];
        float4 b4 = *(const float4*)&Bq[kk][tx * 4];
        float av[2] = {a2.x, a2.y};
        float bv[4] = {b4.x, b4.y, b4.z, b4.w};
#pragma unroll
        for (int i = 0; i < 2; ++i)
#pragma unroll
          for (int j = 0; j < 4; ++j) acc[i][j] = fmaf(av[i], bv[j], acc[i][j]);
      }
      __syncthreads();
    }
    int c0 = n0 + tx * 4;
    float* dst = (wsel == 0) ? q : (wsel == 1) ? ek : vv;
#pragma unroll
    for (int i = 0; i < 2; ++i) {
      int gr = m0 + ty * 2 + i;
      if (gr < NTOK) {
        float4 o;
        if (wsel == 0) {
          o.x = 1.0f / (1.0f + expf(-acc[i][0]));
          o.y = 1.0f / (1.0f + expf(-acc[i][1]));
          o.z = 1.0f / (1.0f + expf(-acc[i][2]));
          o.w = 1.0f / (1.0f + expf(-acc[i][3]));
        } else if (wsel == 1) {
          o.x = expf(acc[i][0]); o.y = expf(acc[i][1]);
          o.z = expf(acc[i][2]); o.w = expf(acc[i][3]);
        } else {
          o.x = acc[i][0]; o.y = acc[i][1]; o.z = acc[i][2]; o.w = acc[i][3];
        }
        *(float4*)&dst[gr * DIM + c0] = o;
      }
    }
  }
}

// ========== K2: agg FULL-K + gate -> attn, grid (98,2), 256 thr ==========
// Block: 8 rows x 64 d-cols, K=784 in 25 chunks of 32 (reg-prefetched).
// A-panel (8 W-rows, 25 KB) staged once. No partial buffers, no second pass.
__global__ __launch_bounds__(256) void agg_full(
    const float* __restrict__ W, const float* __restrict__ ek,
    const float* __restrict__ vv, const float* __restrict__ q,
    float* __restrict__ attn) {
  __shared__ float Wt[8 * 784];    // 25.1 KB
  __shared__ float Bd[32][68];     // 8.7 KB (padded stride 68)
  __shared__ float Bn[32][68];     // 8.7 KB
  int tid = threadIdx.x;
  int m0 = blockIdx.x * 8, d0 = blockIdx.y * 64;

  // stage full A-panel: 8 rows x 784, coalesced
#pragma unroll
  for (int j = 0; j < 7; ++j) {
    int idx = j * 256 + tid;
    if (idx < 1568) {
      int r = idx / 196, c4 = (idx % 196) * 4;
      float4 a = *(const float4*)&W[(m0 + r) * NTOK + c4];
      *(float4*)&Wt[r * 784 + c4] = a;
    }
  }

  int ks = tid >> 4, d4 = (tid & 15) * 4;   // staging coords
  float4 pe0, pe1, pv0, pv1;
  {  // prefetch chunk 0 (full, nk=32)
    pe0 = *(const float4*)&ek[(ks)*DIM + d0 + d4];
    pv0 = *(const float4*)&vv[(ks)*DIM + d0 + d4];
    pe1 = *(const float4*)&ek[(16 + ks) * DIM + d0 + d4];
    pv1 = *(const float4*)&vv[(16 + ks) * DIM + d0 + d4];
  }

  int row = tid >> 5, c2 = (tid & 31) * 2;
  float an0 = 0.f, an1 = 0.f, ad0 = 0.f, ad1 = 0.f;
  const float* wr = &Wt[row * 784];

  for (int c = 0; c < 25; ++c) {
    int k0 = c * 32;
    int nk = (k0 + 32 <= NTOK) ? 32 : (NTOK - k0);   // 32 or 16
    // write staged chunk
    if (ks < nk) {
      Bd[ks][d4 + 0] = pe0.x; Bd[ks][d4 + 1] = pe0.y; Bd[ks][d4 + 2] = pe0.z; Bd[ks][d4 + 3] = pe0.w;
      Bn[ks][d4 + 0] = pe0.x * pv0.x; Bn[ks][d4 + 1] = pe0.y * pv0.y;
      Bn[ks][d4 + 2] = pe0.z * pv0.z; Bn[ks][d4 + 3] = pe0.w * pv0.w;
    }
    if (16 + ks < nk) {
      Bd[16 + ks][d4 + 0] = pe1.x; Bd[16 + ks][d4 + 1] = pe1.y;
      Bd[16 + ks][d4 + 2] = pe1.z; Bd[16 + ks][d4 + 3] = pe1.w;
      Bn[16 + ks][d4 + 0] = pe1.x * pv1.x; Bn[16 + ks][d4 + 1] = pe1.y * pv1.y;
      Bn[16 + ks][d4 + 2] = pe1.z * pv1.z; Bn[16 + ks][d4 + 3] = pe1.w * pv1.w;
    }
    __syncthreads();
    // prefetch next chunk
    if (c < 24) {
      int kn = (c + 1) * 32;
      int nkn = (kn + 32 <= NTOK) ? 32 : (NTOK - kn);
      if (ks < nkn) {
        pe0 = *(const float4*)&ek[(kn + ks) * DIM + d0 + d4];
        pv0 = *(const float4*)&vv[(kn + ks) * DIM + d0 + d4];
      }
      if (16 + ks < nkn) {
        pe1 = *(const float4*)&ek[(kn + 16 + ks) * DIM + d0 + d4];
        pv1 = *(const float4*)&vv[(kn + 16 + ks) * DIM + d0 + d4];
      }
    }
    // MAC
    if (nk == 32) {
#pragma unroll 8
      for (int kk = 0; kk < 32; ++kk) {
        float a = wr[k0 + kk];
        float2 bn = *(const float2*)&Bn[kk][c2];
        float2 bd = *(const float2*)&Bd[kk][c2];
        an0 = fmaf(a, bn.x, an0); an1 = fmaf(a, bn.y, an1);
        ad0 = fmaf(a, bd.x, ad0); ad1 = fmaf(a, bd.y, ad1);
      }
    } else {
#pragma unroll 8
      for (int kk = 0; kk < 16; ++kk) {
        float a = wr[k0 + kk];
        float2 bn = *(const float2*)&Bn[kk][c2];
        float2 bd = *(const float2*)&Bd[kk][c2];
        an0 = fmaf(a, bn.x, an0); an1 = fmaf(a, bn.y, an1);
        ad0 = fmaf(a, bd.x, ad0); ad1 = fmaf(a, bd.y, ad1);
      }
    }
    __syncthreads();
  }

  // gate + write
  int gn = m0 + row;
  int cc = d0 + c2;
  float2 qv = *(const float2*)&q[gn * DIM + cc];
  float2 o = {qv.x * (an0 / ad0), qv.y * (an1 / ad1)};
  *(float2*)&attn[gn * DIM + cc] = o;
}

// ========== K3: O-proj + residual + LN2 + out-init, 98 blocks x 256 thr ==========
__global__ __launch_bounds__(256) void proj_ln(
    const float* __restrict__ attn, const float* __restrict__ wo,
    const float* __restrict__ bo, const float* __restrict__ x,
    const float* __restrict__ g2, const float* __restrict__ b2n,
    const float* __restrict__ b2f, float* __restrict__ fn, float* __restrict__ out) {
  __shared__ float At[DIM][9];     // attn tile k-major, 8 rows
  __shared__ float Bs[DIM][DIM];   // full wo, k-major
  int tid = threadIdx.x;
  int m0 = blockIdx.x * 8;         // 98*8 = 784

  {
    int nn = tid >> 5, c4 = (tid & 31) * 4;
    float4 av = *(const float4*)&attn[(m0 + nn) * DIM + c4];
    At[c4 + 0][nn] = av.x; At[c4 + 1][nn] = av.y;
    At[c4 + 2][nn] = av.z; At[c4 + 3][nn] = av.w;
  }
  {
    int r = tid >> 1, kq = (tid & 1) * 64;
#pragma unroll
    for (int j = 0; j < 16; ++j) {
      float4 v = *(const float4*)&wo[r * DIM + kq + j * 4];
      Bs[kq + j * 4 + 0][r] = v.x; Bs[kq + j * 4 + 1][r] = v.y;
      Bs[kq + j * 4 + 2][r] = v.z; Bs[kq + j * 4 + 3][r] = v.w;
    }
  }
  __syncthreads();

  int ty = tid >> 5, tx = tid & 31;
  float acc[4] = {0.f, 0.f, 0.f, 0.f};
#pragma unroll 4
  for (int kk = 0; kk < DIM; ++kk) {
    float a = At[kk][ty];
    float4 b4 = *(const float4*)&Bs[kk][tx * 4];
    acc[0] = fmaf(a, b4.x, acc[0]);
    acc[1] = fmaf(a, b4.y, acc[1]);
    acc[2] = fmaf(a, b4.z, acc[2]);
    acc[3] = fmaf(a, b4.w, acc[3]);
  }
  int gn = m0 + ty;
  int c0 = tx * 4;
  float4 bias = *(const float4*)&bo[c0];
  float o0 = acc[0] + bias.x + x[(c0 + 0) * NTOK + gn];
  float o1 = acc[1] + bias.y + x[(c0 + 1) * NTOK + gn];
  float o2 = acc[2] + bias.z + x[(c0 + 2) * NTOK + gn];
  float o3 = acc[3] + bias.w + x[(c0 + 3) * NTOK + gn];

  // out-init: out^T = t2 + b2f (ff2 partials atomically added by K4)
  float4 bf = *(const float4*)&b2f[c0];
  out[(c0 + 0) * NTOK + gn] = o0 + bf.x;
  out[(c0 + 1) * NTOK + gn] = o1 + bf.y;
  out[(c0 + 2) * NTOK + gn] = o2 + bf.z;
  out[(c0 + 3) * NTOK + gn] = o3 + bf.w;

  float s = o0 + o1 + o2 + o3;
  float ss = o0 * o0 + o1 * o1 + o2 * o2 + o3 * o3;
#pragma unroll
  for (int off = 1; off < 32; off <<= 1) {
    s += __shfl_xor(s, off);
    ss += __shfl_xor(ss, off);
  }
  float mu = s * (1.0f / DIM);
  float var = ss * (1.0f / DIM) - mu * mu;
  float rs = rsqrtf(var + 1e-5f);
  float4 gg = *(const float4*)&g2[c0];
  float4 bb = *(const float4*)&b2n[c0];
  float4 f;
  f.x = (o0 - mu) * rs * gg.x + bb.x;
  f.y = (o1 - mu) * rs * gg.y + bb.y;
  f.z = (o2 - mu) * rs * gg.z + bb.z;
  f.w = (o3 - mu) * rs * gg.w + bb.w;
  *(float4*)&fn[gn * DIM + c0] = f;
}

// ========== K4: ff1(gelu)+ff2 fused, grid (49, 8), 256 thr, atomic accumulate ==========
__global__ __launch_bounds__(256) void ff_fused16(
    const float* __restrict__ fn, const float* __restrict__ w1,
    const float* __restrict__ b1f, const float* __restrict__ w2,
    float* __restrict__ out) {
  __shared__ float Fs[DIM][16];
  __shared__ float W1s[DIM][64];   // reused as W2s[64][128]
  __shared__ float P[16][65];
  int tid = threadIdx.x;
  int m0 = blockIdx.x * 16, f0 = blockIdx.y * 64;

  {
    int r = tid >> 4, kq = (tid & 15) * 8;
#pragma unroll
    for (int j = 0; j < 2; ++j) {
      float4 v = *(const float4*)&fn[(m0 + r) * DIM + kq + j * 4];
      Fs[kq + j * 4 + 0][r] = v.x; Fs[kq + j * 4 + 1][r] = v.y;
      Fs[kq + j * 4 + 2][r] = v.z; Fs[kq + j * 4 + 3][r] = v.w;
    }
    int rw = tid >> 2, kw = (tid & 3) * 32;
#pragma unroll
    for (int j = 0; j < 8; ++j) {
      float4 v = *(const float4*)&w1[(f0 + rw) * DIM + kw + j * 4];
      W1s[kw + j * 4 + 0][rw] = v.x; W1s[kw + j * 4 + 1][rw] = v.y;
      W1s[kw + j * 4 + 2][rw] = v.z; W1s[kw + j * 4 + 3][rw] = v.w;
    }
  }
  __syncthreads();

  int row = tid >> 4, f4 = (tid & 15) * 4;
  float acc1[4] = {};
#pragma unroll 4
  for (int kk = 0; kk < DIM; ++kk) {
    float a = Fs[kk][row];
    float4 b4 = *(const float4*)&W1s[kk][f4];
    acc1[0] = fmaf(a, b4.x, acc1[0]);
    acc1[1] = fmaf(a, b4.y, acc1[1]);
    acc1[2] = fmaf(a, b4.z, acc1[2]);
    acc1[3] = fmaf(a, b4.w, acc1[3]);
  }
  float4 b1v = *(const float4*)&b1f[f0 + f4];
  float bb[4] = {b1v.x, b1v.y, b1v.z, b1v.w};
  float ge[4];
#pragma unroll
  for (int j = 0; j < 4; ++j) {
    float v = acc1[j] + bb[j];
    ge[j] = 0.5f * v * (1.0f + erff(v * 0.70710678118654752f));
  }
  __syncthreads();

#pragma unroll
  for (int j = 0; j < 4; ++j) P[row][f4 + j] = ge[j];
  float* W2s = &W1s[0][0];
  {
    int c = tid >> 1, fq = (tid & 1) * 32;
#pragma unroll
    for (int j = 0; j < 8; ++j) {
      float4 v = *(const float4*)&w2[c * FFD + f0 + fq + j * 4];
      W2s[(fq + j * 4 + 0) * DIM + c] = v.x;
      W2s[(fq + j * 4 + 1) * DIM + c] = v.y;
      W2s[(fq + j * 4 + 2) * DIM + c] = v.z;
      W2s[(fq + j * 4 + 3) * DIM + c] = v.w;
    }
  }
  __syncthreads();

  int r2 = tid & 15, cb = (tid >> 4) * 8;
  float acc2[8] = {};
  for (int f = 0; f < 64; ++f) {
    float pvv = P[r2][f];
    const float* wr = &W2s[f * DIM + cb];
#pragma unroll
    for (int j4 = 0; j4 < 2; ++j4) {
      float4 wv = *(const float4*)&wr[j4 * 4];
      acc2[j4 * 4 + 0] = fmaf(pvv, wv.x, acc2[j4 * 4 + 0]);
      acc2[j4 * 4 + 1] = fmaf(pvv, wv.y, acc2[j4 * 4 + 1]);
      acc2[j4 * 4 + 2] = fmaf(pvv, wv.z, acc2[j4 * 4 + 2]);
      acc2[j4 * 4 + 3] = fmaf(pvv, wv.w, acc2[j4 * 4 + 3]);
    }
  }
#pragma unroll
  for (int j = 0; j < 8; ++j)
    atomicAdd(&out[(cb + j) * NTOK + m0 + r2], acc2[j]);
}

extern "C" void kernel_launch(void* const* d_in, const int* in_sizes, int n_in,
                              void* d_out, int out_size, void* d_ws, size_t ws_size,
                              hipStream_t stream) {
  const float* x   = (const float*)d_in[0];
  const float* wq  = (const float*)d_in[1];
  const float* wk  = (const float*)d_in[2];
  const float* wv  = (const float*)d_in[3];
  const float* wo  = (const float*)d_in[4];
  const float* bo  = (const float*)d_in[5];
  const float* pu  = (const float*)d_in[6];
  const float* pv  = (const float*)d_in[7];
  const float* g1  = (const float*)d_in[8];
  const float* b1n = (const float*)d_in[9];
  const float* g2  = (const float*)d_in[10];
  const float* b2n = (const float*)d_in[11];
  const float* w1  = (const float*)d_in[12];
  const float* b1f = (const float*)d_in[13];
  const float* w2  = (const float*)d_in[14];
  const float* b2f = (const float*)d_in[15];
  float* out = (float*)d_out;

  float* ws = (float*)d_ws;
  float* q    = ws;                 // [784,128]
  float* ek   = ws + 100352;        // [784,128]
  float* vv   = ws + 200704;        // [784,128]
  float* fn   = ws + 301056;        // [784,128]
  float* attn = ws + 401408;        // [784,128]
  float* W    = ws + 501760;        // [784,784]

  posw_qkv3<<<475, 256, 0, stream>>>(pu, pv, W, x, g1, b1n, wq, wk, wv, q, ek, vv);
  agg_full<<<dim3(98, 2), 256, 0, stream>>>(W, ek, vv, q, attn);
  proj_ln<<<98, 256, 0, stream>>>(attn, wo, bo, x, g2, b2n, b2f, fn, out);
  ff_fused16<<<dim3(49, 8), 256, 0, stream>>>(fn, w1, b1f, w2, out);
}

// Round 11
// 51.657 us; speedup vs baseline: 1.5053x; 1.3136x over previous
//
#include <hip/hip_runtime.h>
#include <math.h>

#define NTOK 784
#define DIM 128
#define FFD 512

// ========== K1: posw (325 blocks, 32x64) || LN1+qkv (150 blocks, 32 rows) ==========
__global__ __launch_bounds__(256) void posw_qkv3(
    const float* __restrict__ pu, const float* __restrict__ pv, float* __restrict__ W,
    const float* __restrict__ x, const float* __restrict__ g, const float* __restrict__ b,
    const float* __restrict__ wq, const float* __restrict__ wk, const float* __restrict__ wv,
    float* __restrict__ q, float* __restrict__ ek, float* __restrict__ vv) {
  __shared__ float smem[12288];  // 48 KB union
  int tid = threadIdx.x;

  if (blockIdx.x < 325) {
    float (*As)[32] = (float(*)[32])smem;           // [128][32]
    float (*Bs)[64] = (float(*)[64])(smem + 4096);  // [128][64]
    int m0 = (blockIdx.x % 25) * 32, n0 = (blockIdx.x / 25) * 64;
    {
      int r = tid >> 3, kq = (tid & 7) * 16;
      int gm = min(m0 + r, NTOK - 1);
#pragma unroll
      for (int j = 0; j < 4; ++j) {
        float4 a = *(const float4*)&pu[gm * DIM + kq + j * 4];
        As[kq + j * 4 + 0][r] = a.x; As[kq + j * 4 + 1][r] = a.y;
        As[kq + j * 4 + 2][r] = a.z; As[kq + j * 4 + 3][r] = a.w;
      }
      int rb = tid >> 2, kb = (tid & 3) * 32;
      int gn = min(n0 + rb, NTOK - 1);
#pragma unroll
      for (int j = 0; j < 8; ++j) {
        float4 v = *(const float4*)&pv[gn * DIM + kb + j * 4];
        Bs[kb + j * 4 + 0][rb] = v.x; Bs[kb + j * 4 + 1][rb] = v.y;
        Bs[kb + j * 4 + 2][rb] = v.z; Bs[kb + j * 4 + 3][rb] = v.w;
      }
    }
    __syncthreads();
    int tx = tid & 15, ty = tid >> 4;  // 2 rows x 4 cols per thread
    float acc[2][4] = {};
#pragma unroll 8
    for (int kk = 0; kk < DIM; ++kk) {
      float2 a2 = *(const float2*)&As[kk][ty * 2];
      float4 b4 = *(const float4*)&Bs[kk][tx * 4];
      float av[2] = {a2.x, a2.y};
      float bv[4] = {b4.x, b4.y, b4.z, b4.w};
#pragma unroll
      for (int i = 0; i < 2; ++i)
#pragma unroll
        for (int j = 0; j < 4; ++j) acc[i][j] = fmaf(av[i], bv[j], acc[i][j]);
    }
    int c0 = n0 + tx * 4;
    if (c0 + 3 < NTOK) {
#pragma unroll
      for (int i = 0; i < 2; ++i) {
        int gr = m0 + ty * 2 + i;
        if (gr < NTOK) {
          float4 o = {expf(acc[i][0]), expf(acc[i][1]), expf(acc[i][2]), expf(acc[i][3])};
          *(float4*)&W[gr * NTOK + c0] = o;
        }
      }
    }
  } else {
    float (*Xs)[32] = (float(*)[32])smem;            // [128][32]
    float (*Bq)[64] = (float(*)[64])(smem + 4096);   // [64][64]
    float* redS = smem + 8192;
    float* redQ = smem + 8448;
    int bid = blockIdx.x - 325;
    int m0 = (bid % 25) * 32;
    int ct = bid / 25;
    int wsel = ct >> 1;
    int n0 = (ct & 1) * 64;
    const float* B = (wsel == 0) ? wq : (wsel == 1) ? wk : wv;

    if (m0 + 32 <= NTOK) {
#pragma unroll
      for (int it = 0; it < 4; ++it) {
        int idx = it * 256 + tid;
        int c = idx >> 3, j4 = (idx & 7) * 4;
        float4 v = *(const float4*)&x[c * NTOK + m0 + j4];
        Xs[c][j4 + 0] = v.x; Xs[c][j4 + 1] = v.y; Xs[c][j4 + 2] = v.z; Xs[c][j4 + 3] = v.w;
      }
    } else {
#pragma unroll
      for (int it = 0; it < 4; ++it) {
        int idx = it * 256 + tid;
        int c = idx >> 3, j4 = (idx & 7) * 4;
#pragma unroll
        for (int u = 0; u < 4; ++u) {
          int n = min(m0 + j4 + u, NTOK - 1);
          Xs[c][j4 + u] = x[c * NTOK + n];
        }
      }
    }
    __syncthreads();

    int n = tid & 31, grp = tid >> 5;
    float s = 0.f, ss = 0.f;
    for (int c = grp * 16; c < grp * 16 + 16; ++c) { float v = Xs[c][n]; s += v; ss += v * v; }
    redS[grp * 32 + n] = s; redQ[grp * 32 + n] = ss;
    __syncthreads();
    float sum = 0.f, sq = 0.f;
#pragma unroll
    for (int gi = 0; gi < 8; ++gi) { sum += redS[gi * 32 + n]; sq += redQ[gi * 32 + n]; }
    float mu = sum * (1.0f / DIM);
    float var = sq * (1.0f / DIM) - mu * mu;
    float rs = rsqrtf(var + 1e-5f);
    for (int c = grp * 16; c < grp * 16 + 16; ++c)
      Xs[c][n] = (Xs[c][n] - mu) * rs * g[c] + b[c];

    int tx = tid & 15, ty = tid >> 4;
    float acc[2][4] = {};
#pragma unroll
    for (int h = 0; h < 2; ++h) {
      {
        int r = tid >> 2, kq = (tid & 3) * 16;
#pragma unroll
        for (int j = 0; j < 4; ++j) {
          float4 v = *(const float4*)&B[(n0 + r) * DIM + h * 64 + kq + j * 4];
          Bq[kq + j * 4 + 0][r] = v.x; Bq[kq + j * 4 + 1][r] = v.y;
          Bq[kq + j * 4 + 2][r] = v.z; Bq[kq + j * 4 + 3][r] = v.w;
        }
      }
      __syncthreads();
#pragma unroll 4
      for (int kk = 0; kk < 64; ++kk) {
        float2 a2 = *(const float2*)&Xs[h * 64 + kk][ty * 2];
        float4 b4 = *(const float4*)&Bq[kk][tx * 4];
        float av[2] = {a2.x, a2.y};
        float bv[4] = {b4.x, b4.y, b4.z, b4.w};
#pragma unroll
        for (int i = 0; i < 2; ++i)
#pragma unroll
          for (int j = 0; j < 4; ++j) acc[i][j] = fmaf(av[i], bv[j], acc[i][j]);
      }
      __syncthreads();
    }
    int c0 = n0 + tx * 4;
    float* dst = (wsel == 0) ? q : (wsel == 1) ? ek : vv;
#pragma unroll
    for (int i = 0; i < 2; ++i) {
      int gr = m0 + ty * 2 + i;
      if (gr < NTOK) {
        float4 o;
        if (wsel == 0) {
          o.x = 1.0f / (1.0f + expf(-acc[i][0]));
          o.y = 1.0f / (1.0f + expf(-acc[i][1]));
          o.z = 1.0f / (1.0f + expf(-acc[i][2]));
          o.w = 1.0f / (1.0f + expf(-acc[i][3]));
        } else if (wsel == 1) {
          o.x = expf(acc[i][0]); o.y = expf(acc[i][1]);
          o.z = expf(acc[i][2]); o.w = expf(acc[i][3]);
        } else {
          o.x = acc[i][0]; o.y = acc[i][1]; o.z = acc[i][2]; o.w = acc[i][3];
        }
        *(float4*)&dst[gr * DIM + c0] = o;
      }
    }
  }
}

// ========== K2: agg, m-tile 64, split-8, grid (13,2,8), 256 thr, 3-chunk batch ==========
// 4x4 register tile: 32 FMA / 24 LDS-clk per kk -> VALU-bound. float4 LDS writes.
__global__ __launch_bounds__(256) void agg64(
    const float* __restrict__ W, const float* __restrict__ ek,
    const float* __restrict__ vv, float* __restrict__ nump, float* __restrict__ denp) {
  __shared__ float As[96][64];
  __shared__ float Bn[96][64];
  __shared__ float Bd[96][64];
  int tid = threadIdx.x;
  int m0 = blockIdx.x * 64, d0 = blockIdx.y * 64, sp = blockIdx.z;
  int tx = tid & 15, ty = tid >> 4;        // 4 rows x 4 cols per thread
  int ra = tid >> 2, ka = (tid & 3) * 8;   // A: 64 rows x 32 k per chunk
  int kb = tid >> 3, db = (tid & 7) * 8;   // B: 32 k x 64 d per chunk
  int gm = min(m0 + ra, NTOK - 1);
  float an[4][4] = {}, ad[4][4] = {};
  int tlo = (sp * 25) / 8, thi = ((sp + 1) * 25) / 8;
  for (int base = tlo; base < thi; base += 3) {
    int nt = min(3, thi - base);
    for (int t = 0; t < nt; ++t) {
      int k0 = (base + t) * 32;
      int lk = t * 32;
      if (k0 + 32 <= NTOK) {
        float4 a0 = *(const float4*)&W[gm * NTOK + k0 + ka];
        float4 a1 = *(const float4*)&W[gm * NTOK + k0 + ka + 4];
        As[lk + ka + 0][ra] = a0.x; As[lk + ka + 1][ra] = a0.y;
        As[lk + ka + 2][ra] = a0.z; As[lk + ka + 3][ra] = a0.w;
        As[lk + ka + 4][ra] = a1.x; As[lk + ka + 5][ra] = a1.y;
        As[lk + ka + 6][ra] = a1.z; As[lk + ka + 7][ra] = a1.w;
        int gk = k0 + kb;
        float4 e0 = *(const float4*)&ek[gk * DIM + d0 + db];
        float4 e1 = *(const float4*)&ek[gk * DIM + d0 + db + 4];
        float4 w0 = *(const float4*)&vv[gk * DIM + d0 + db];
        float4 w1_ = *(const float4*)&vv[gk * DIM + d0 + db + 4];
        *(float4*)&Bd[lk + kb][db] = e0;
        *(float4*)&Bd[lk + kb][db + 4] = e1;
        float4 n0v = {e0.x * w0.x, e0.y * w0.y, e0.z * w0.z, e0.w * w0.w};
        float4 n1v = {e1.x * w1_.x, e1.y * w1_.y, e1.z * w1_.z, e1.w * w1_.w};
        *(float4*)&Bn[lk + kb][db] = n0v;
        *(float4*)&Bn[lk + kb][db + 4] = n1v;
      } else {
#pragma unroll
        for (int j = 0; j < 8; ++j) {
          int gk = k0 + ka + j;
          As[lk + ka + j][ra] = (gk < NTOK) ? W[gm * NTOK + gk] : 0.f;
        }
        int gk = k0 + kb;
        if (gk < NTOK) {
          float4 e0 = *(const float4*)&ek[gk * DIM + d0 + db];
          float4 e1 = *(const float4*)&ek[gk * DIM + d0 + db + 4];
          float4 w0 = *(const float4*)&vv[gk * DIM + d0 + db];
          float4 w1_ = *(const float4*)&vv[gk * DIM + d0 + db + 4];
          *(float4*)&Bd[lk + kb][db] = e0;
          *(float4*)&Bd[lk + kb][db + 4] = e1;
          float4 n0v = {e0.x * w0.x, e0.y * w0.y, e0.z * w0.z, e0.w * w0.w};
          float4 n1v = {e1.x * w1_.x, e1.y * w1_.y, e1.z * w1_.z, e1.w * w1_.w};
          *(float4*)&Bn[lk + kb][db] = n0v;
          *(float4*)&Bn[lk + kb][db + 4] = n1v;
        } else {
          float4 z = {0.f, 0.f, 0.f, 0.f};
          *(float4*)&Bd[lk + kb][db] = z; *(float4*)&Bd[lk + kb][db + 4] = z;
          *(float4*)&Bn[lk + kb][db] = z; *(float4*)&Bn[lk + kb][db + 4] = z;
        }
      }
    }
    __syncthreads();
    int nk = nt * 32;
    for (int kk = 0; kk < nk; ++kk) {
      float4 a4 = *(const float4*)&As[kk][ty * 4];
      float4 n4 = *(const float4*)&Bn[kk][tx * 4];
      float4 d4 = *(const float4*)&Bd[kk][tx * 4];
      float av[4] = {a4.x, a4.y, a4.z, a4.w};
      float nv[4] = {n4.x, n4.y, n4.z, n4.w};
      float dv[4] = {d4.x, d4.y, d4.z, d4.w};
#pragma unroll
      for (int i = 0; i < 4; ++i)
#pragma unroll
        for (int j = 0; j < 4; ++j) {
          an[i][j] = fmaf(av[i], nv[j], an[i][j]);
          ad[i][j] = fmaf(av[i], dv[j], ad[i][j]);
        }
    }
    __syncthreads();
  }
#pragma unroll
  for (int i = 0; i < 4; ++i) {
    int gr = m0 + ty * 4 + i;
    if (gr < NTOK) {
      float4 on = {an[i][0], an[i][1], an[i][2], an[i][3]};
      float4 od = {ad[i][0], ad[i][1], ad[i][2], ad[i][3]};
      *(float4*)&nump[(sp * NTOK + gr) * DIM + d0 + tx * 4] = on;
      *(float4*)&denp[(sp * NTOK + gr) * DIM + d0 + tx * 4] = od;
    }
  }
}

// ========== K3: gate + O-proj + residual + LN2 + out-init, 98 blocks x 256 thr ==========
__global__ __launch_bounds__(256) void gate_proj_ln(
    const float* __restrict__ q, const float* __restrict__ nump,
    const float* __restrict__ denp, const float* __restrict__ wo,
    const float* __restrict__ bo, const float* __restrict__ x,
    const float* __restrict__ g2, const float* __restrict__ b2n,
    const float* __restrict__ b2f, float* __restrict__ fn, float* __restrict__ out) {
  __shared__ float At[DIM][9];     // attn tile k-major, 8 rows
  __shared__ float Bs[DIM][DIM];   // full wo, k-major
  int tid = threadIdx.x;
  int m0 = blockIdx.x * 8;         // 98*8 = 784

  {
    int nn = tid >> 5, c4 = (tid & 31) * 4;
    int base = (m0 + nn) * DIM + c4;
    float4 qv = *(const float4*)&q[base];
    float4 nv = {0.f, 0.f, 0.f, 0.f}, dv = {0.f, 0.f, 0.f, 0.f};
#pragma unroll
    for (int s = 0; s < 8; ++s) {
      float4 a = *(const float4*)&nump[s * NTOK * DIM + base];
      float4 d = *(const float4*)&denp[s * NTOK * DIM + base];
      nv.x += a.x; nv.y += a.y; nv.z += a.z; nv.w += a.w;
      dv.x += d.x; dv.y += d.y; dv.z += d.z; dv.w += d.w;
    }
    At[c4 + 0][nn] = qv.x * (nv.x / dv.x);
    At[c4 + 1][nn] = qv.y * (nv.y / dv.y);
    At[c4 + 2][nn] = qv.z * (nv.z / dv.z);
    At[c4 + 3][nn] = qv.w * (nv.w / dv.w);
  }
  {
    int r = tid >> 1, kq = (tid & 1) * 64;
#pragma unroll
    for (int j = 0; j < 16; ++j) {
      float4 v = *(const float4*)&wo[r * DIM + kq + j * 4];
      Bs[kq + j * 4 + 0][r] = v.x; Bs[kq + j * 4 + 1][r] = v.y;
      Bs[kq + j * 4 + 2][r] = v.z; Bs[kq + j * 4 + 3][r] = v.w;
    }
  }
  __syncthreads();

  int ty = tid >> 5, tx = tid & 31;
  float acc[4] = {0.f, 0.f, 0.f, 0.f};
#pragma unroll 4
  for (int kk = 0; kk < DIM; ++kk) {
    float a = At[kk][ty];
    float4 b4 = *(const float4*)&Bs[kk][tx * 4];
    acc[0] = fmaf(a, b4.x, acc[0]);
    acc[1] = fmaf(a, b4.y, acc[1]);
    acc[2] = fmaf(a, b4.z, acc[2]);
    acc[3] = fmaf(a, b4.w, acc[3]);
  }
  int gn = m0 + ty;
  int c0 = tx * 4;
  float4 bias = *(const float4*)&bo[c0];
  float o0 = acc[0] + bias.x + x[(c0 + 0) * NTOK + gn];
  float o1 = acc[1] + bias.y + x[(c0 + 1) * NTOK + gn];
  float o2 = acc[2] + bias.z + x[(c0 + 2) * NTOK + gn];
  float o3 = acc[3] + bias.w + x[(c0 + 3) * NTOK + gn];

  float4 bf = *(const float4*)&b2f[c0];
  out[(c0 + 0) * NTOK + gn] = o0 + bf.x;
  out[(c0 + 1) * NTOK + gn] = o1 + bf.y;
  out[(c0 + 2) * NTOK + gn] = o2 + bf.z;
  out[(c0 + 3) * NTOK + gn] = o3 + bf.w;

  float s = o0 + o1 + o2 + o3;
  float ss = o0 * o0 + o1 * o1 + o2 * o2 + o3 * o3;
#pragma unroll
  for (int off = 1; off < 32; off <<= 1) {
    s += __shfl_xor(s, off);
    ss += __shfl_xor(ss, off);
  }
  float mu = s * (1.0f / DIM);
  float var = ss * (1.0f / DIM) - mu * mu;
  float rs = rsqrtf(var + 1e-5f);
  float4 gg = *(const float4*)&g2[c0];
  float4 bb = *(const float4*)&b2n[c0];
  float4 f;
  f.x = (o0 - mu) * rs * gg.x + bb.x;
  f.y = (o1 - mu) * rs * gg.y + bb.y;
  f.z = (o2 - mu) * rs * gg.z + bb.z;
  f.w = (o3 - mu) * rs * gg.w + bb.w;
  *(float4*)&fn[gn * DIM + c0] = f;
}

// ========== K4: ff1(gelu)+ff2 fused, grid (49, 8), 256 thr, atomic accumulate ==========
__global__ __launch_bounds__(256) void ff_fused16(
    const float* __restrict__ fn, const float* __restrict__ w1,
    const float* __restrict__ b1f, const float* __restrict__ w2,
    float* __restrict__ out) {
  __shared__ float Fs[DIM][16];
  __shared__ float W1s[DIM][64];   // reused as W2s[64][128]
  __shared__ float P[16][65];
  int tid = threadIdx.x;
  int m0 = blockIdx.x * 16, f0 = blockIdx.y * 64;

  {
    int r = tid >> 4, kq = (tid & 15) * 8;
#pragma unroll
    for (int j = 0; j < 2; ++j) {
      float4 v = *(const float4*)&fn[(m0 + r) * DIM + kq + j * 4];
      Fs[kq + j * 4 + 0][r] = v.x; Fs[kq + j * 4 + 1][r] = v.y;
      Fs[kq + j * 4 + 2][r] = v.z; Fs[kq + j * 4 + 3][r] = v.w;
    }
    int rw = tid >> 2, kw = (tid & 3) * 32;
#pragma unroll
    for (int j = 0; j < 8; ++j) {
      float4 v = *(const float4*)&w1[(f0 + rw) * DIM + kw + j * 4];
      W1s[kw + j * 4 + 0][rw] = v.x; W1s[kw + j * 4 + 1][rw] = v.y;
      W1s[kw + j * 4 + 2][rw] = v.z; W1s[kw + j * 4 + 3][rw] = v.w;
    }
  }
  __syncthreads();

  int row = tid >> 4, f4 = (tid & 15) * 4;
  float acc1[4] = {};
#pragma unroll 4
  for (int kk = 0; kk < DIM; ++kk) {
    float a = Fs[kk][row];
    float4 b4 = *(const float4*)&W1s[kk][f4];
    acc1[0] = fmaf(a, b4.x, acc1[0]);
    acc1[1] = fmaf(a, b4.y, acc1[1]);
    acc1[2] = fmaf(a, b4.z, acc1[2]);
    acc1[3] = fmaf(a, b4.w, acc1[3]);
  }
  float4 b1v = *(const float4*)&b1f[f0 + f4];
  float bb[4] = {b1v.x, b1v.y, b1v.z, b1v.w};
  float ge[4];
#pragma unroll
  for (int j = 0; j < 4; ++j) {
    float v = acc1[j] + bb[j];
    ge[j] = 0.5f * v * (1.0f + erff(v * 0.70710678118654752f));
  }
  __syncthreads();

#pragma unroll
  for (int j = 0; j < 4; ++j) P[row][f4 + j] = ge[j];
  float* W2s = &W1s[0][0];
  {
    int c = tid >> 1, fq = (tid & 1) * 32;
#pragma unroll
    for (int j = 0; j < 8; ++j) {
      float4 v = *(const float4*)&w2[c * FFD + f0 + fq + j * 4];
      W2s[(fq + j * 4 + 0) * DIM + c] = v.x;
      W2s[(fq + j * 4 + 1) * DIM + c] = v.y;
      W2s[(fq + j * 4 + 2) * DIM + c] = v.z;
      W2s[(fq + j * 4 + 3) * DIM + c] = v.w;
    }
  }
  __syncthreads();

  int r2 = tid & 15, cb = (tid >> 4) * 8;
  float acc2[8] = {};
  for (int f = 0; f < 64; ++f) {
    float pvv = P[r2][f];
    const float* wr = &W2s[f * DIM + cb];
#pragma unroll
    for (int j4 = 0; j4 < 2; ++j4) {
      float4 wv = *(const float4*)&wr[j4 * 4];
      acc2[j4 * 4 + 0] = fmaf(pvv, wv.x, acc2[j4 * 4 + 0]);
      acc2[j4 * 4 + 1] = fmaf(pvv, wv.y, acc2[j4 * 4 + 1]);
      acc2[j4 * 4 + 2] = fmaf(pvv, wv.z, acc2[j4 * 4 + 2]);
      acc2[j4 * 4 + 3] = fmaf(pvv, wv.w, acc2[j4 * 4 + 3]);
    }
  }
#pragma unroll
  for (int j = 0; j < 8; ++j)
    atomicAdd(&out[(cb + j) * NTOK + m0 + r2], acc2[j]);
}

extern "C" void kernel_launch(void* const* d_in, const int* in_sizes, int n_in,
                              void* d_out, int out_size, void* d_ws, size_t ws_size,
                              hipStream_t stream) {
  const float* x   = (const float*)d_in[0];
  const float* wq  = (const float*)d_in[1];
  const float* wk  = (const float*)d_in[2];
  const float* wv  = (const float*)d_in[3];
  const float* wo  = (const float*)d_in[4];
  const float* bo  = (const float*)d_in[5];
  const float* pu  = (const float*)d_in[6];
  const float* pv  = (const float*)d_in[7];
  const float* g1  = (const float*)d_in[8];
  const float* b1n = (const float*)d_in[9];
  const float* g2  = (const float*)d_in[10];
  const float* b2n = (const float*)d_in[11];
  const float* w1  = (const float*)d_in[12];
  const float* b1f = (const float*)d_in[13];
  const float* w2  = (const float*)d_in[14];
  const float* b2f = (const float*)d_in[15];
  float* out = (float*)d_out;

  float* ws = (float*)d_ws;
  float* q    = ws;                 // [784,128]
  float* ek   = ws + 100352;        // [784,128]
  float* vv   = ws + 200704;        // [784,128]
  float* fn   = ws + 301056;        // [784,128]
  float* W    = ws + 401408;        // [784,784]
  float* nump = ws + 1016064;       // [8,784,128]
  float* denp = ws + 1818880;       // [8,784,128]

  posw_qkv3<<<475, 256, 0, stream>>>(pu, pv, W, x, g1, b1n, wq, wk, wv, q, ek, vv);
  agg64<<<dim3(13, 2, 8), 256, 0, stream>>>(W, ek, vv, nump, denp);
  gate_proj_ln<<<98, 256, 0, stream>>>(q, nump, denp, wo, bo, x, g2, b2n, b2f, fn, out);
  ff_fused16<<<dim3(49, 8), 256, 0, stream>>>(fn, w1, b1f, w2, out);
}